// Round 7
// baseline (66.977 us; speedup 1.0000x reference)
//
#include <hip/hip_runtime.h>
#include <hip/hip_bf16.h>
#include <math.h>

#define B_ROWS 16384
#define DIM 1024

typedef __attribute__((ext_vector_type(8))) short s16x8;
typedef __attribute__((ext_vector_type(4))) float f32x4;

static __device__ __forceinline__ unsigned short f2bf(float f) {
    union { float f; unsigned u; } v; v.f = f;
    unsigned r = v.u + 0x7FFF + ((v.u >> 16) & 1);  // RNE
    return (unsigned short)(r >> 16);
}

// packed f32x2 -> bf16x2 (RNE), single HW instruction
static __device__ __forceinline__ unsigned cvt_pk_bf16(float lo, float hi) {
    unsigned r;
    asm volatile("v_cvt_pk_bf16_f32 %0, %1, %2" : "=v"(r) : "v"(lo), "v"(hi));
    return r;
}

// async global -> LDS, 16 bytes per lane; lds base wave-uniform, HW adds lane*16
static __device__ __forceinline__ void gload16(const unsigned short* g, unsigned short* l) {
    __builtin_amdgcn_global_load_lds(
        (const __attribute__((address_space(1))) unsigned int*)g,
        (__attribute__((address_space(3))) unsigned int*)l, 16, 0, 0);
}

// ---------------------------------------------------------------------------
// prep (178 blocks): weight transpose+convert+pad (64x64 LDS tiles) +
// cross-net P-vector rows into W1b spare rows + scalar constants czz[6].
// Cross-net closed form (exact algebra):
//   z_i = s^3(x.P3_i)+s^2(x.P2_i)+s(x.P1_i)+(x.Wl)+s^2 C2_i+s C1_i+C0_i
// W1b rows: 500:P3_0 501:P2_0 502:P1_0 503:P3_1 504:P2_1 505:P1_1 506:Wl
//           507:ones (row-sum s)  508-511: zero
// ---------------------------------------------------------------------------
__global__ __launch_bounds__(256) void prep(
    const float* __restrict__ W1, const float* __restrict__ W2,
    const float* __restrict__ W3,
    const float* __restrict__ cw, const float* __restrict__ cb,
    const float* __restrict__ Wl,
    unsigned short* __restrict__ W1b, unsigned short* __restrict__ W2b,
    unsigned short* __restrict__ W3b,
    float* __restrict__ czz) {
    __shared__ unsigned short tile[64][72];
    __shared__ float red[4][6];
    const int tid = threadIdx.x;
    const int blk = blockIdx.x;

    if (blk < 176) {
        const int w = blk;
        const float* src; unsigned short* dst;
        int kt, nt, Ksrc, Nsrc, ldDst;
        bool skipHi = false;
        if (w < 128)      { kt = w & 15;         nt = w >> 4;         src = W1; dst = W1b; Ksrc = 1024; Nsrc = 500; ldDst = 1024; skipHi = true; }
        else if (w < 160) { kt = (w - 128) & 7;  nt = (w - 128) >> 3; src = W2; dst = W2b; Ksrc = 500;  Nsrc = 200; ldDst = 512;  }
        else              { kt = (w - 160) & 3;  nt = (w - 160) >> 2; src = W3; dst = W3b; Ksrc = 200;  Nsrc = 200; ldDst = 256;  }
        const int k0 = kt << 6, n0 = nt << 6;
        {
            const int r = tid >> 2, c0 = (tid & 3) << 4;
            const int kk = k0 + r;
#pragma unroll
            for (int i = 0; i < 16; ++i) {
                const int nn = n0 + c0 + i;
                const float v = (kk < Ksrc && nn < Nsrc) ? src[(size_t)kk * Nsrc + nn] : 0.f;
                tile[r][c0 + i] = f2bf(v);
            }
        }
        __syncthreads();
        {
            const int n = tid >> 2, kc = (tid & 3) << 4;
            if (!(skipHi && (n0 + n) >= 500)) {   // rows 500-511 owned by blk 176
                unsigned short* o = dst + (size_t)(n0 + n) * ldDst + k0 + kc;
#pragma unroll
                for (int i = 0; i < 16; ++i) o[i] = tile[kc + i][n];
            }
        }
    } else if (blk == 176) {
        // ---- P-vector rows ----
#pragma unroll
        for (int q = 0; q < 4; ++q) {
            const int k = tid * 4 + q;
            const float wl = Wl[k];
            const float a1 = cw[k],         a2 = cw[1024 + k],  a3 = cw[2048 + k];
            const float d1_ = cw[3072 + k], d2_ = cw[4096 + k], d3_ = cw[5120 + k];
            W1b[(size_t)500 * 1024 + k] = f2bf(a1 * a2 * a3 * wl);
            W1b[(size_t)501 * 1024 + k] = f2bf(a2 * a3 * wl);
            W1b[(size_t)502 * 1024 + k] = f2bf(a3 * wl);
            W1b[(size_t)503 * 1024 + k] = f2bf(d1_ * d2_ * d3_ * wl);
            W1b[(size_t)504 * 1024 + k] = f2bf(d2_ * d3_ * wl);
            W1b[(size_t)505 * 1024 + k] = f2bf(d3_ * wl);
            W1b[(size_t)506 * 1024 + k] = f2bf(wl);
            W1b[(size_t)507 * 1024 + k] = 0x3F80;   // bf16 1.0
            W1b[(size_t)508 * 1024 + k] = 0;
            W1b[(size_t)509 * 1024 + k] = 0;
            W1b[(size_t)510 * 1024 + k] = 0;
            W1b[(size_t)511 * 1024 + k] = 0;
        }
    } else {
        // ---- C scalars (f32 exact) ----
        float c[6] = {0.f, 0.f, 0.f, 0.f, 0.f, 0.f};
#pragma unroll
        for (int q = 0; q < 4; ++q) {
            const int k = tid * 4 + q;
            const float wl = Wl[k];
            {
                const float w2 = cw[1024 + k], w3 = cw[2048 + k];
                const float b1 = cb[k], b2 = cb[1024 + k], b3 = cb[2048 + k];
                c[0] += w2 * w3 * b1 * wl;
                c[1] += w3 * b2 * wl;
                c[2] += b3 * wl;
            }
            {
                const float w2 = cw[4096 + k], w3 = cw[5120 + k];
                const float b1 = cb[3072 + k], b2 = cb[4096 + k], b3 = cb[5120 + k];
                c[3] += w2 * w3 * b1 * wl;
                c[4] += w3 * b2 * wl;
                c[5] += b3 * wl;
            }
        }
        const int lane = tid & 63, wv = tid >> 6;
#pragma unroll
        for (int j = 0; j < 6; ++j)
#pragma unroll
            for (int m = 1; m < 64; m <<= 1) c[j] += __shfl_xor(c[j], m, 64);
        if (lane == 0)
#pragma unroll
            for (int j = 0; j < 6; ++j) red[wv][j] = c[j];
        __syncthreads();
        if (tid < 6) czz[tid] = red[0][tid] + red[1][tid] + red[2][tid] + red[3][tid];
    }
}

// ---------------------------------------------------------------------------
// stage_tile (4-wave): global_load_lds dwordx4, pre-swizzled global source,
// linear LDS dest.  LDS: [row][64] bf16, 16B chunk c holds k-chunk c^(row&7).
// ---------------------------------------------------------------------------
template <int ROWS>
static __device__ __forceinline__ void stage_tile(
    const unsigned short* __restrict__ src, int K, int rowBase, int kt,
    unsigned short* lds, int w, int lane) {
    const int r8   = lane >> 3;
    const int slot = lane & 7;
#pragma unroll
    for (int q = 0; q < ROWS / 32; ++q) {
        const int blk   = q * 4 + w;
        const int row   = blk * 8 + r8;
        const int chunk = slot ^ (row & 7);
        const unsigned short* g = src + (size_t)(rowBase + row) * K + kt * 64 + chunk * 8;
        gload16(g, lds + blk * 512);
    }
}

// stage (8-wave / 512-thread variant)
template <int ROWS>
static __device__ __forceinline__ void stage8(
    const unsigned short* __restrict__ src, int K, int rowBase, int kt,
    unsigned short* lds, int w, int lane) {
    const int r8   = lane >> 3;
    const int slot = lane & 7;
#pragma unroll
    for (int q = 0; q < ROWS / 64; ++q) {
        const int blk   = q * 8 + w;
        const int row   = blk * 8 + r8;
        const int chunk = slot ^ (row & 7);
        const unsigned short* g = src + (size_t)(rowBase + row) * K + kt * 64 + chunk * 8;
        gload16(g, lds + blk * 512);
    }
}

// ---------------------------------------------------------------------------
// gemm_xa: d1 = relu(x @ W1 + b1) reading x as f32 DIRECTLY (no xb pass).
// Tile 128x128, BK=64, 4 waves (2x2).  A: reg-staged f32 (8x dwordx4/thread,
// issued one tile ahead) -> v_cvt_pk_bf16_f32 -> swizzled ds_write_b128.
// B: global_load_lds.  One barrier per K-step; counted vmcnt.
// Cols 500-507 spill raw f32 accumulators to zparts (cross-net dots + xsum).
// ---------------------------------------------------------------------------
__global__ __launch_bounds__(256) void gemm_xa(
    const float* __restrict__ X,             // 16384 x 1024 f32
    const unsigned short* __restrict__ Bw,   // 512 x 1024 bf16 (N x K)
    const float* __restrict__ bias,          // b1 (500)
    unsigned short* __restrict__ C,          // 16384 x 512 bf16
    float* __restrict__ zparts) {            // B_ROWS x 8 f32
    constexpr int K = 1024, ldc = 512, BM = 128, nK = 16;
    __shared__ unsigned short As[2][BM * 64];
    __shared__ unsigned short Bs[2][128 * 64];

    const int tid  = threadIdx.x;
    const int lane = tid & 63;
    const int wid  = tid >> 6;
    const int wm   = wid >> 1;
    const int wn   = wid & 1;
    const int g    = lane >> 4;
    const int r16  = lane & 15;

    const int cpx = gridDim.x >> 3;
    const int swz = (blockIdx.x & 7) * cpx + (blockIdx.x >> 3);
    const int rowBase = (swz >> 2) * BM;       // 4 col tiles (512/128)
    const int colBase = (swz & 3) << 7;

    // A staging mapping: thread covers 32 consecutive f32 of one row
    const int arow  = tid >> 1;                // 0..127
    const int ahalf = tid & 1;                 // k-half (32 f32)
    const float* aSrc = X + (size_t)(rowBase + arow) * K + ahalf * 32;
    const int arw = arow & 7;

    float4 a_regs[8];

    f32x4 acc[4][4];
#pragma unroll
    for (int m = 0; m < 4; ++m)
#pragma unroll
        for (int n = 0; n < 4; ++n)
            acc[m][n] = (f32x4){0.f, 0.f, 0.f, 0.f};

    // ---- prologue ----
    {   // issue A(0)
        const float* s = aSrc;
#pragma unroll
        for (int i = 0; i < 8; ++i) a_regs[i] = *(const float4*)(s + i * 4);
    }
    asm volatile("" ::: "memory");
    stage_tile<128>(Bw, K, colBase, 0, Bs[0], wid, lane);   // B(0)
    asm volatile("" ::: "memory");
    {   // cvt+write A(0) -> As[0]   (compiler inserts vmcnt for a_regs)
#pragma unroll
        for (int j = 0; j < 4; ++j) {
            uint4 v;
            v.x = cvt_pk_bf16(a_regs[2 * j].x, a_regs[2 * j].y);
            v.y = cvt_pk_bf16(a_regs[2 * j].z, a_regs[2 * j].w);
            v.z = cvt_pk_bf16(a_regs[2 * j + 1].x, a_regs[2 * j + 1].y);
            v.w = cvt_pk_bf16(a_regs[2 * j + 1].z, a_regs[2 * j + 1].w);
            const int ch = (ahalf * 4 + j) ^ arw;
            *(uint4*)((char*)As[0] + arow * 128 + ch * 16) = v;
        }
    }
    asm volatile("" ::: "memory");
    {   // issue A(1)
        const float* s = aSrc + 64;
#pragma unroll
        for (int i = 0; i < 8; ++i) a_regs[i] = *(const float4*)(s + i * 4);
    }
    asm volatile("s_waitcnt vmcnt(8)" ::: "memory");   // B(0) done; A(1) in flight
    asm volatile("s_waitcnt lgkmcnt(0)" ::: "memory"); // A(0) ds_writes done
    __builtin_amdgcn_s_barrier();
    asm volatile("" ::: "memory");

    // ---- main loop: one barrier per K-step ----
    for (int kt = 0; kt < nK; ++kt) {
        const int buf = kt & 1;
        if (kt + 1 < nK) {
            stage_tile<128>(Bw, K, colBase, kt + 1, Bs[buf ^ 1], wid, lane);
            asm volatile("" ::: "memory");
        }

        // compute(kt)
        const unsigned short* Ab = As[buf];
        const unsigned short* Bb = Bs[buf];
#pragma unroll
        for (int ks = 0; ks < 2; ++ks) {
            s16x8 af[4], bfr[4];
#pragma unroll
            for (int m = 0; m < 4; ++m) {
                const int row = wm * 64 + m * 16 + r16;
                const int off = ((ks * 4 + g) * 16) ^ ((row & 7) << 4);
                af[m] = *(const s16x8*)((const char*)Ab + row * 128 + off);
            }
#pragma unroll
            for (int n = 0; n < 4; ++n) {
                const int row = wn * 64 + n * 16 + r16;
                const int off = ((ks * 4 + g) * 16) ^ ((row & 7) << 4);
                bfr[n] = *(const s16x8*)((const char*)Bb + row * 128 + off);
            }
#pragma unroll
            for (int m = 0; m < 4; ++m)
#pragma unroll
                for (int n = 0; n < 4; ++n)
                    acc[m][n] = __builtin_amdgcn_mfma_f32_16x16x32_bf16(af[m], bfr[n], acc[m][n], 0, 0, 0);
        }

        if (kt + 1 < nK) {
            // cvt + ds_write A(kt+1) -> As[buf^1]  (compiler waits a_regs)
#pragma unroll
            for (int j = 0; j < 4; ++j) {
                uint4 v;
                v.x = cvt_pk_bf16(a_regs[2 * j].x, a_regs[2 * j].y);
                v.y = cvt_pk_bf16(a_regs[2 * j].z, a_regs[2 * j].w);
                v.z = cvt_pk_bf16(a_regs[2 * j + 1].x, a_regs[2 * j + 1].y);
                v.w = cvt_pk_bf16(a_regs[2 * j + 1].z, a_regs[2 * j + 1].w);
                const int ch = (ahalf * 4 + j) ^ arw;
                *(uint4*)((char*)As[buf ^ 1] + arow * 128 + ch * 16) = v;
            }
            asm volatile("" ::: "memory");
            if (kt + 2 < nK) {
                const float* s = aSrc + (kt + 2) * 64;
#pragma unroll
                for (int i = 0; i < 8; ++i) a_regs[i] = *(const float4*)(s + i * 4);
                asm volatile("s_waitcnt vmcnt(8)" ::: "memory");  // B(kt+1) done
            } else {
                asm volatile("s_waitcnt vmcnt(0)" ::: "memory");
            }
        } else {
            asm volatile("s_waitcnt vmcnt(0)" ::: "memory");
        }
        asm volatile("s_waitcnt lgkmcnt(0)" ::: "memory");
        __builtin_amdgcn_s_barrier();
        asm volatile("" ::: "memory");
    }

    // ---- epilogue: bias + relu + bf16 store; cols 500-507 -> zparts raw ----
#pragma unroll
    for (int n = 0; n < 4; ++n) {
        const int col = colBase + wn * 64 + n * 16 + r16;
        const float bv = (col < 500) ? bias[col] : 0.f;
        const unsigned pc = (unsigned)(col - 500);
#pragma unroll
        for (int m = 0; m < 4; ++m) {
            const int rowB = rowBase + wm * 64 + m * 16 + g * 4;
#pragma unroll
            for (int r = 0; r < 4; ++r) {
                const float raw = acc[m][n][r];
                float v = raw + bv;
                v = v > 0.f ? v : 0.f;
                C[(size_t)(rowB + r) * ldc + col] = f2bf(v);
                if (pc < 8u) zparts[(size_t)(rowB + r) * 8 + pc] = raw;
            }
        }
    }
}

// ---------------------------------------------------------------------------
// tail_fused (8 waves / 512 threads, 2M x 4N wave grid): per 64-row block —
//   phase 1: P = relu(d1[64x512] @ W2b^T + b2)  (64x256 bf16 in LDS)
//   phase 2: acc2 = P @ W3b^T
//   epilogue: tail = relu(acc2 + b3) . Wl[1024:]
//   final: z_i = Horner(zparts, s) + czz_i + tail + bl; out = sigmoid(z_i)
// ---------------------------------------------------------------------------
__global__ __launch_bounds__(512) void tail_fused(
    const unsigned short* __restrict__ d1,   // 16384 x 512 bf16
    const unsigned short* __restrict__ W2b,  // 256 x 512 bf16 (N x K)
    const float* __restrict__ b2,
    const unsigned short* __restrict__ W3b,  // 256 x 256 bf16 (N x K)
    const float* __restrict__ b3,
    const float* __restrict__ Wl,            // 1224 floats
    const float* __restrict__ bl,
    const float* __restrict__ zparts,        // B_ROWS x 8
    const float* __restrict__ czz,           // 6
    float* __restrict__ out) {
    __shared__ unsigned short As[2][64 * 64];
    __shared__ unsigned short Bs[2][256 * 64];
    __shared__ unsigned short P[64 * 256];
    __shared__ float part[8][64];

    const int tid  = threadIdx.x;
    const int lane = tid & 63;
    const int wid  = tid >> 6;     // 0..7
    const int wm   = wid >> 2;     // 0..1 (rows)
    const int wn   = wid & 3;      // 0..3 (cols)
    const int g    = lane >> 4;
    const int r16  = lane & 15;
    const int rowBase = blockIdx.x << 6;

    f32x4 acc[2][4];
#pragma unroll
    for (int m = 0; m < 2; ++m)
#pragma unroll
        for (int n = 0; n < 4; ++n)
            acc[m][n] = (f32x4){0.f, 0.f, 0.f, 0.f};

    // ---- phase 1: d1[64x512] @ W2b(256x512) ----
    stage8<64>(d1, 512, rowBase, 0, As[0], wid, lane);
    stage8<256>(W2b, 512, 0, 0, Bs[0], wid, lane);

    for (int kt = 0; kt < 8; ++kt) {
        const int buf = kt & 1;
        if (kt + 1 < 8) {
            stage8<64>(d1, 512, rowBase, kt + 1, As[buf ^ 1], wid, lane);
            stage8<256>(W2b, 512, 0, kt + 1, Bs[buf ^ 1], wid, lane);
            asm volatile("s_waitcnt vmcnt(5)" ::: "memory");
        } else {
            asm volatile("s_waitcnt vmcnt(0)" ::: "memory");
        }
        __builtin_amdgcn_s_barrier();
        asm volatile("" ::: "memory");

        const unsigned short* Ab = As[buf];
        const unsigned short* Bb = Bs[buf];
#pragma unroll
        for (int ks = 0; ks < 2; ++ks) {
            s16x8 af[2], bfr[4];
#pragma unroll
            for (int m = 0; m < 2; ++m) {
                const int row = wm * 32 + m * 16 + r16;
                const int off = ((ks * 4 + g) * 16) ^ ((row & 7) << 4);
                af[m] = *(const s16x8*)((const char*)Ab + row * 128 + off);
            }
#pragma unroll
            for (int n = 0; n < 4; ++n) {
                const int row = wn * 64 + n * 16 + r16;
                const int off = ((ks * 4 + g) * 16) ^ ((row & 7) << 4);
                bfr[n] = *(const s16x8*)((const char*)Bb + row * 128 + off);
            }
#pragma unroll
            for (int m = 0; m < 2; ++m)
#pragma unroll
                for (int n = 0; n < 4; ++n)
                    acc[m][n] = __builtin_amdgcn_mfma_f32_16x16x32_bf16(af[m], bfr[n], acc[m][n], 0, 0, 0);
        }
        asm volatile("s_waitcnt lgkmcnt(0)" ::: "memory");
        __builtin_amdgcn_s_barrier();
        asm volatile("" ::: "memory");
    }

    // ---- phase-1 epilogue: bias + relu + bf16 -> P (XOR-swizzled) ----
#pragma unroll
    for (int n = 0; n < 4; ++n) {
        const int col = wn * 64 + n * 16 + r16;
        const float bv = (col < 200) ? b2[col] : 0.f;
#pragma unroll
        for (int m = 0; m < 2; ++m) {
#pragma unroll
            for (int r = 0; r < 4; ++r) {
                const int row = wm * 32 + m * 16 + g * 4 + r;
                float v = acc[m][n][r] + bv;
                v = v > 0.f ? v : 0.f;
                const int byte = row * 512 + ((col * 2) ^ ((row & 7) << 4));
                *(unsigned short*)((char*)P + byte) = f2bf(v);
            }
        }
    }

    // ---- phase 2: P(64x256) @ W3b(256x256) ----
    stage8<256>(W3b, 256, 0, 0, Bs[0], wid, lane);
    asm volatile("s_waitcnt lgkmcnt(0)" ::: "memory");  // P writes done
    __builtin_amdgcn_s_barrier();
    asm volatile("" ::: "memory");

    f32x4 acc2[2][4];
#pragma unroll
    for (int m = 0; m < 2; ++m)
#pragma unroll
        for (int n = 0; n < 4; ++n)
            acc2[m][n] = (f32x4){0.f, 0.f, 0.f, 0.f};

    for (int kt = 0; kt < 4; ++kt) {
        const int buf = kt & 1;
        if (kt + 1 < 4) {
            stage8<256>(W3b, 256, 0, kt + 1, Bs[buf ^ 1], wid, lane);
            asm volatile("s_waitcnt vmcnt(4)" ::: "memory");
        } else {
            asm volatile("s_waitcnt vmcnt(0)" ::: "memory");
        }
        __builtin_amdgcn_s_barrier();
        asm volatile("" ::: "memory");

        const unsigned short* Bb = Bs[buf];
#pragma unroll
        for (int ks = 0; ks < 2; ++ks) {
            s16x8 af[2], bfr[4];
#pragma unroll
            for (int m = 0; m < 2; ++m) {
                const int row = wm * 32 + m * 16 + r16;
                const int byte = row * 512 + ((kt * 128 + (ks * 4 + g) * 16) ^ ((row & 7) << 4));
                af[m] = *(const s16x8*)((const char*)P + byte);
            }
#pragma unroll
            for (int n = 0; n < 4; ++n) {
                const int row = wn * 64 + n * 16 + r16;
                const int off = ((ks * 4 + g) * 16) ^ ((row & 7) << 4);
                bfr[n] = *(const s16x8*)((const char*)Bb + row * 128 + off);
            }
#pragma unroll
            for (int m = 0; m < 2; ++m)
#pragma unroll
                for (int n = 0; n < 4; ++n)
                    acc2[m][n] = __builtin_amdgcn_mfma_f32_16x16x32_bf16(af[m], bfr[n], acc2[m][n], 0, 0, 0);
        }
        asm volatile("s_waitcnt lgkmcnt(0)" ::: "memory");
        __builtin_amdgcn_s_barrier();
        asm volatile("" ::: "memory");
    }

    // ---- tail dot ----
    float wlv[4], b3v[4];
#pragma unroll
    for (int n = 0; n < 4; ++n) {
        const int col = wn * 64 + n * 16 + r16;
        wlv[n] = (col < 200) ? Wl[1024 + col] : 0.f;
        b3v[n] = (col < 200) ? b3[col] : 0.f;
    }
#pragma unroll
    for (int m = 0; m < 2; ++m) {
#pragma unroll
        for (int r = 0; r < 4; ++r) {
            float s = 0.f;
#pragma unroll
            for (int n = 0; n < 4; ++n) {
                float v = acc2[m][n][r] + b3v[n];
                v = v > 0.f ? v : 0.f;
                s += v * wlv[n];
            }
            s += __shfl_xor(s, 1, 64);
            s += __shfl_xor(s, 2, 64);
            s += __shfl_xor(s, 4, 64);
            s += __shfl_xor(s, 8, 64);
            if (r16 == 0) part[wid][wm * 32 + m * 16 + g * 4 + r] = s;
        }
    }
    __syncthreads();

    // ---- final: cross-net Horner combine + sigmoid ----
    if (tid < 64) {
        const int row = rowBase + tid;
        const int wmr = (tid >> 5) << 2;
        const float t = part[wmr][tid] + part[wmr + 1][tid] +
                        part[wmr + 2][tid] + part[wmr + 3][tid];
        const float blv = bl[0];
        const float* zp = zparts + (size_t)row * 8;
        float4 zpa = *(const float4*)(zp);       // P3_0 P2_0 P1_0 P3_1
        float4 zpb = *(const float4*)(zp + 4);   // P2_1 P1_1 P0   s
        const float s = zpb.w;
        const float z0 = ((zpa.x * s + zpa.y + czz[0]) * s + zpa.z + czz[1]) * s
                         + zpb.z + czz[2] + t + blv;
        const float z1 = ((zpa.w * s + zpb.x + czz[3]) * s + zpb.y + czz[4]) * s
                         + zpb.z + czz[5] + t + blv;
        out[row]          = 1.f / (1.f + expf(-z0));
        out[B_ROWS + row] = 1.f / (1.f + expf(-z1));
    }
}

// ---------------------------------------------------------------------------
extern "C" void kernel_launch(void* const* d_in, const int* in_sizes, int n_in,
                              void* d_out, int out_size, void* d_ws, size_t ws_size,
                              hipStream_t stream) {
    const float* x  = (const float*)d_in[0];
    const float* W1 = (const float*)d_in[3];
    const float* b1 = (const float*)d_in[4];
    const float* W2 = (const float*)d_in[5];
    const float* b2 = (const float*)d_in[6];
    const float* W3 = (const float*)d_in[7];
    const float* b3 = (const float*)d_in[8];
    const float* Wl = (const float*)d_in[9];
    const float* bl = (const float*)d_in[10];
    const float* cw = (const float*)d_in[11];
    const float* cb = (const float*)d_in[12];
    float* out = (float*)d_out;

    unsigned short* d1  = (unsigned short*)d_ws;          // 16384 x 512
    unsigned short* W1b = d1 + (size_t)16384 * 512;       // 512 x 1024
    unsigned short* W2b = W1b + (size_t)512 * 1024;       // 256 x 512
    unsigned short* W3b = W2b + (size_t)256 * 512;        // 256 x 256
    float* zparts = (float*)(W3b + (size_t)256 * 256);    // 16384 x 8
    float* czz = zparts + (size_t)16384 * 8;              // 6

    // weight transpose + cross-net P-vectors/constants
    prep<<<178, 256, 0, stream>>>(W1, W2, W3, cw, cb, Wl, W1b, W2b, W3b, czz);

    // d1 = relu(x @ W1 + b1), x read as f32 directly; cross dots -> zparts
    gemm_xa<<<512, 256, 0, stream>>>(x, W1b, b1, d1, zparts);

    // d2/d3/tail/cross-combine/sigmoid fused
    tail_fused<<<256, 512, 0, stream>>>(d1, W2b, b2, W3b, b3, Wl, bl,
                                        zparts, czz, out);
}

// Round 8
// 54.509 us; speedup vs baseline: 1.2287x; 1.2287x over previous
//
#include <hip/hip_runtime.h>
#include <hip/hip_bf16.h>
#include <math.h>

#define B_ROWS 16384
#define DIM 1024

typedef __attribute__((ext_vector_type(8))) short s16x8;
typedef __attribute__((ext_vector_type(4))) float f32x4;

static __device__ __forceinline__ unsigned short f2bf(float f) {
    union { float f; unsigned u; } v; v.f = f;
    unsigned r = v.u + 0x7FFF + ((v.u >> 16) & 1);  // RNE
    return (unsigned short)(r >> 16);
}

// packed f32x2 -> bf16x2 (RNE), single HW instruction
static __device__ __forceinline__ unsigned cvt_pk_bf16(float lo, float hi) {
    unsigned r;
    asm volatile("v_cvt_pk_bf16_f32 %0, %1, %2" : "=v"(r) : "v"(lo), "v"(hi));
    return r;
}

// async global -> LDS, 16 bytes per lane; lds base wave-uniform, HW adds lane*16
static __device__ __forceinline__ void gload16(const unsigned short* g, unsigned short* l) {
    __builtin_amdgcn_global_load_lds(
        (const __attribute__((address_space(1))) unsigned int*)g,
        (__attribute__((address_space(3))) unsigned int*)l, 16, 0, 0);
}

// ---------------------------------------------------------------------------
// prep (178 blocks): weight transpose+convert+pad (64x64 LDS tiles) +
// cross-net P-vector rows into W1b spare rows + scalar constants czz[6].
// Cross-net closed form (exact algebra):
//   z_i = s^3(x.P3_i)+s^2(x.P2_i)+s(x.P1_i)+(x.Wl)+s^2 C2_i+s C1_i+C0_i
// W1b rows: 500:P3_0 501:P2_0 502:P1_0 503:P3_1 504:P2_1 505:P1_1 506:Wl
//           507:ones (row-sum s)  508-511: zero
// ---------------------------------------------------------------------------
__global__ __launch_bounds__(256) void prep(
    const float* __restrict__ W1, const float* __restrict__ W2,
    const float* __restrict__ W3,
    const float* __restrict__ cw, const float* __restrict__ cb,
    const float* __restrict__ Wl,
    unsigned short* __restrict__ W1b, unsigned short* __restrict__ W2b,
    unsigned short* __restrict__ W3b,
    float* __restrict__ czz) {
    __shared__ unsigned short tile[64][72];
    __shared__ float red[4][6];
    const int tid = threadIdx.x;
    const int blk = blockIdx.x;

    if (blk < 176) {
        const int w = blk;
        const float* src; unsigned short* dst;
        int kt, nt, Ksrc, Nsrc, ldDst;
        bool skipHi = false;
        if (w < 128)      { kt = w & 15;         nt = w >> 4;         src = W1; dst = W1b; Ksrc = 1024; Nsrc = 500; ldDst = 1024; skipHi = true; }
        else if (w < 160) { kt = (w - 128) & 7;  nt = (w - 128) >> 3; src = W2; dst = W2b; Ksrc = 500;  Nsrc = 200; ldDst = 512;  }
        else              { kt = (w - 160) & 3;  nt = (w - 160) >> 2; src = W3; dst = W3b; Ksrc = 200;  Nsrc = 200; ldDst = 256;  }
        const int k0 = kt << 6, n0 = nt << 6;
        {
            const int r = tid >> 2, c0 = (tid & 3) << 4;
            const int kk = k0 + r;
#pragma unroll
            for (int i = 0; i < 16; ++i) {
                const int nn = n0 + c0 + i;
                const float v = (kk < Ksrc && nn < Nsrc) ? src[(size_t)kk * Nsrc + nn] : 0.f;
                tile[r][c0 + i] = f2bf(v);
            }
        }
        __syncthreads();
        {
            const int n = tid >> 2, kc = (tid & 3) << 4;
            if (!(skipHi && (n0 + n) >= 500)) {   // rows 500-511 owned by blk 176
                unsigned short* o = dst + (size_t)(n0 + n) * ldDst + k0 + kc;
#pragma unroll
                for (int i = 0; i < 16; ++i) o[i] = tile[kc + i][n];
            }
        }
    } else if (blk == 176) {
        // ---- P-vector rows ----
#pragma unroll
        for (int q = 0; q < 4; ++q) {
            const int k = tid * 4 + q;
            const float wl = Wl[k];
            const float a1 = cw[k],         a2 = cw[1024 + k],  a3 = cw[2048 + k];
            const float d1_ = cw[3072 + k], d2_ = cw[4096 + k], d3_ = cw[5120 + k];
            W1b[(size_t)500 * 1024 + k] = f2bf(a1 * a2 * a3 * wl);
            W1b[(size_t)501 * 1024 + k] = f2bf(a2 * a3 * wl);
            W1b[(size_t)502 * 1024 + k] = f2bf(a3 * wl);
            W1b[(size_t)503 * 1024 + k] = f2bf(d1_ * d2_ * d3_ * wl);
            W1b[(size_t)504 * 1024 + k] = f2bf(d2_ * d3_ * wl);
            W1b[(size_t)505 * 1024 + k] = f2bf(d3_ * wl);
            W1b[(size_t)506 * 1024 + k] = f2bf(wl);
            W1b[(size_t)507 * 1024 + k] = 0x3F80;   // bf16 1.0
            W1b[(size_t)508 * 1024 + k] = 0;
            W1b[(size_t)509 * 1024 + k] = 0;
            W1b[(size_t)510 * 1024 + k] = 0;
            W1b[(size_t)511 * 1024 + k] = 0;
        }
    } else {
        // ---- C scalars (f32 exact) ----
        float c[6] = {0.f, 0.f, 0.f, 0.f, 0.f, 0.f};
#pragma unroll
        for (int q = 0; q < 4; ++q) {
            const int k = tid * 4 + q;
            const float wl = Wl[k];
            {
                const float w2 = cw[1024 + k], w3 = cw[2048 + k];
                const float b1 = cb[k], b2 = cb[1024 + k], b3 = cb[2048 + k];
                c[0] += w2 * w3 * b1 * wl;
                c[1] += w3 * b2 * wl;
                c[2] += b3 * wl;
            }
            {
                const float w2 = cw[4096 + k], w3 = cw[5120 + k];
                const float b1 = cb[3072 + k], b2 = cb[4096 + k], b3 = cb[5120 + k];
                c[3] += w2 * w3 * b1 * wl;
                c[4] += w3 * b2 * wl;
                c[5] += b3 * wl;
            }
        }
        const int lane = tid & 63, wv = tid >> 6;
#pragma unroll
        for (int j = 0; j < 6; ++j)
#pragma unroll
            for (int m = 1; m < 64; m <<= 1) c[j] += __shfl_xor(c[j], m, 64);
        if (lane == 0)
#pragma unroll
            for (int j = 0; j < 6; ++j) red[wv][j] = c[j];
        __syncthreads();
        if (tid < 6) czz[tid] = red[0][tid] + red[1][tid] + red[2][tid] + red[3][tid];
    }
}

// ---------------------------------------------------------------------------
// stage_tile (4-wave): global_load_lds dwordx4, pre-swizzled global source,
// linear LDS dest.  LDS: [row][64] bf16, 16B chunk c holds k-chunk c^(row&7).
// ---------------------------------------------------------------------------
template <int ROWS>
static __device__ __forceinline__ void stage_tile(
    const unsigned short* __restrict__ src, int K, int rowBase, int kt,
    unsigned short* lds, int w, int lane) {
    const int r8   = lane >> 3;
    const int slot = lane & 7;
#pragma unroll
    for (int q = 0; q < ROWS / 32; ++q) {
        const int blk   = q * 4 + w;
        const int row   = blk * 8 + r8;
        const int chunk = slot ^ (row & 7);
        const unsigned short* g = src + (size_t)(rowBase + row) * K + kt * 64 + chunk * 8;
        gload16(g, lds + blk * 512);
    }
}

// stage (8-wave / 512-thread variant)
template <int ROWS>
static __device__ __forceinline__ void stage8(
    const unsigned short* __restrict__ src, int K, int rowBase, int kt,
    unsigned short* lds, int w, int lane) {
    const int r8   = lane >> 3;
    const int slot = lane & 7;
#pragma unroll
    for (int q = 0; q < ROWS / 64; ++q) {
        const int blk   = q * 8 + w;
        const int row   = blk * 8 + r8;
        const int chunk = slot ^ (row & 7);
        const unsigned short* g = src + (size_t)(rowBase + row) * K + kt * 64 + chunk * 8;
        gload16(g, lds + blk * 512);
    }
}

// ---------------------------------------------------------------------------
// gemm_xa: d1 = relu(x @ W1 + b1) reading x as f32 DIRECTLY.
// Tile 128x128, BK=64, 4 waves (2x2).
// A path (COALESCED): round q in [0,8): thread t loads float4 at
//   row = q*16 + (t>>4), f32-offset (t&15)*4  -> 16 lanes cover 256B
//   contiguous per row, 4 rows per wave-instruction (full lines).
// Loads for tile kt+1 issue at the TOP of iter kt (land under compute);
// cvt_pk + swizzled ds_write_b64 after compute.  B: global_load_lds.
// Cols 500-507 spill raw f32 accumulators to zparts (cross dots + xsum).
// ---------------------------------------------------------------------------
__global__ __launch_bounds__(256) void gemm_xa(
    const float* __restrict__ X,             // 16384 x 1024 f32
    const unsigned short* __restrict__ Bw,   // 512 x 1024 bf16 (N x K)
    const float* __restrict__ bias,          // b1 (500)
    unsigned short* __restrict__ C,          // 16384 x 512 bf16
    float* __restrict__ zparts) {            // B_ROWS x 8 f32
    constexpr int K = 1024, ldc = 512, BM = 128, nK = 16;
    __shared__ unsigned short As[2][BM * 64];
    __shared__ unsigned short Bs[2][128 * 64];

    const int tid  = threadIdx.x;
    const int lane = tid & 63;
    const int wid  = tid >> 6;
    const int wm   = wid >> 1;
    const int wn   = wid & 1;
    const int g    = lane >> 4;
    const int r16  = lane & 15;

    const int cpx = gridDim.x >> 3;
    const int swz = (blockIdx.x & 7) * cpx + (blockIdx.x >> 3);
    const int rowBase = (swz >> 2) * BM;       // 4 col tiles (512/128)
    const int colBase = (swz & 3) << 7;

    // coalesced A staging coords
    const int ar16 = tid >> 4;                 // row within 16-row round
    const int ak4  = tid & 15;                 // f32 k-slice (x4)
    const float* aSrc = X + (size_t)(rowBase + ar16) * K + ak4 * 4;

    float4 a_regs[8];

    f32x4 acc[4][4];
#pragma unroll
    for (int m = 0; m < 4; ++m)
#pragma unroll
        for (int n = 0; n < 4; ++n)
            acc[m][n] = (f32x4){0.f, 0.f, 0.f, 0.f};

    // A cvt + swizzled LDS write (b64): row q*16+ar16, chunk (ak4>>1)^(row&7)
    auto cvt_write_A = [&](unsigned short* dst) {
#pragma unroll
        for (int q = 0; q < 8; ++q) {
            const int row = q * 16 + ar16;
            const int ch  = (ak4 >> 1) ^ (row & 7);
            uint2 v;
            v.x = cvt_pk_bf16(a_regs[q].x, a_regs[q].y);
            v.y = cvt_pk_bf16(a_regs[q].z, a_regs[q].w);
            *(uint2*)((char*)dst + row * 128 + ch * 16 + (ak4 & 1) * 8) = v;
        }
    };
    auto issue_A = [&](int kt) {
#pragma unroll
        for (int q = 0; q < 8; ++q)
            a_regs[q] = *(const float4*)(aSrc + (size_t)q * 16 * K + kt * 64);
    };

    // ---- prologue: tile 0 ----
    issue_A(0);
    asm volatile("" ::: "memory");
    stage_tile<128>(Bw, K, colBase, 0, Bs[0], wid, lane);   // B(0)
    asm volatile("" ::: "memory");
    cvt_write_A(As[0]);                       // implicit vmcnt wait on a_regs
    asm volatile("s_waitcnt vmcnt(0)" ::: "memory");
    asm volatile("s_waitcnt lgkmcnt(0)" ::: "memory");
    __builtin_amdgcn_s_barrier();
    asm volatile("" ::: "memory");

    // ---- main loop: one barrier per K-step ----
    for (int kt = 0; kt < nK; ++kt) {
        const int buf = kt & 1;
        if (kt + 1 < nK) {
            issue_A(kt + 1);                  // lands under compute below
            asm volatile("" ::: "memory");
            stage_tile<128>(Bw, K, colBase, kt + 1, Bs[buf ^ 1], wid, lane);
            asm volatile("" ::: "memory");
        }

        // compute(kt)
        const unsigned short* Ab = As[buf];
        const unsigned short* Bb = Bs[buf];
#pragma unroll
        for (int ks = 0; ks < 2; ++ks) {
            s16x8 af[4], bfr[4];
#pragma unroll
            for (int m = 0; m < 4; ++m) {
                const int row = wm * 64 + m * 16 + r16;
                const int off = ((ks * 4 + g) * 16) ^ ((row & 7) << 4);
                af[m] = *(const s16x8*)((const char*)Ab + row * 128 + off);
            }
#pragma unroll
            for (int n = 0; n < 4; ++n) {
                const int row = wn * 64 + n * 16 + r16;
                const int off = ((ks * 4 + g) * 16) ^ ((row & 7) << 4);
                bfr[n] = *(const s16x8*)((const char*)Bb + row * 128 + off);
            }
#pragma unroll
            for (int m = 0; m < 4; ++m)
#pragma unroll
                for (int n = 0; n < 4; ++n)
                    acc[m][n] = __builtin_amdgcn_mfma_f32_16x16x32_bf16(af[m], bfr[n], acc[m][n], 0, 0, 0);
        }

        if (kt + 1 < nK) {
            cvt_write_A(As[buf ^ 1]);         // a_regs landed during compute
        }
        asm volatile("s_waitcnt vmcnt(0)" ::: "memory");   // B(kt+1) complete
        asm volatile("s_waitcnt lgkmcnt(0)" ::: "memory"); // A ds_writes done
        __builtin_amdgcn_s_barrier();
        asm volatile("" ::: "memory");
    }

    // ---- epilogue: bias + relu + bf16 store; cols 500-507 -> zparts raw ----
#pragma unroll
    for (int n = 0; n < 4; ++n) {
        const int col = colBase + wn * 64 + n * 16 + r16;
        const float bv = (col < 500) ? bias[col] : 0.f;
        const unsigned pc = (unsigned)(col - 500);
#pragma unroll
        for (int m = 0; m < 4; ++m) {
            const int rowB = rowBase + wm * 64 + m * 16 + g * 4;
#pragma unroll
            for (int r = 0; r < 4; ++r) {
                const float raw = acc[m][n][r];
                float v = raw + bv;
                v = v > 0.f ? v : 0.f;
                C[(size_t)(rowB + r) * ldc + col] = f2bf(v);
                if (pc < 8u) zparts[(size_t)(rowB + r) * 8 + pc] = raw;
            }
        }
    }
}

// ---------------------------------------------------------------------------
// tail_fused (8 waves / 512 threads, 2M x 4N wave grid): per 64-row block —
//   phase 1: P = relu(d1[64x512] @ W2b^T + b2)  (64x256 bf16 in LDS)
//   phase 2: acc2 = P @ W3b^T
//   epilogue: tail = relu(acc2 + b3) . Wl[1024:]
//   final: z_i = Horner(zparts, s) + czz_i + tail + bl; out = sigmoid(z_i)
// ---------------------------------------------------------------------------
__global__ __launch_bounds__(512) void tail_fused(
    const unsigned short* __restrict__ d1,   // 16384 x 512 bf16
    const unsigned short* __restrict__ W2b,  // 256 x 512 bf16 (N x K)
    const float* __restrict__ b2,
    const unsigned short* __restrict__ W3b,  // 256 x 256 bf16 (N x K)
    const float* __restrict__ b3,
    const float* __restrict__ Wl,            // 1224 floats
    const float* __restrict__ bl,
    const float* __restrict__ zparts,        // B_ROWS x 8
    const float* __restrict__ czz,           // 6
    float* __restrict__ out) {
    __shared__ unsigned short As[2][64 * 64];
    __shared__ unsigned short Bs[2][256 * 64];
    __shared__ unsigned short P[64 * 256];
    __shared__ float part[8][64];

    const int tid  = threadIdx.x;
    const int lane = tid & 63;
    const int wid  = tid >> 6;     // 0..7
    const int wm   = wid >> 2;     // 0..1 (rows)
    const int wn   = wid & 3;      // 0..3 (cols)
    const int g    = lane >> 4;
    const int r16  = lane & 15;
    const int rowBase = blockIdx.x << 6;

    f32x4 acc[2][4];
#pragma unroll
    for (int m = 0; m < 2; ++m)
#pragma unroll
        for (int n = 0; n < 4; ++n)
            acc[m][n] = (f32x4){0.f, 0.f, 0.f, 0.f};

    // ---- phase 1: d1[64x512] @ W2b(256x512) ----
    stage8<64>(d1, 512, rowBase, 0, As[0], wid, lane);
    stage8<256>(W2b, 512, 0, 0, Bs[0], wid, lane);

    for (int kt = 0; kt < 8; ++kt) {
        const int buf = kt & 1;
        if (kt + 1 < 8) {
            stage8<64>(d1, 512, rowBase, kt + 1, As[buf ^ 1], wid, lane);
            stage8<256>(W2b, 512, 0, kt + 1, Bs[buf ^ 1], wid, lane);
            asm volatile("s_waitcnt vmcnt(5)" ::: "memory");
        } else {
            asm volatile("s_waitcnt vmcnt(0)" ::: "memory");
        }
        __builtin_amdgcn_s_barrier();
        asm volatile("" ::: "memory");

        const unsigned short* Ab = As[buf];
        const unsigned short* Bb = Bs[buf];
#pragma unroll
        for (int ks = 0; ks < 2; ++ks) {
            s16x8 af[2], bfr[4];
#pragma unroll
            for (int m = 0; m < 2; ++m) {
                const int row = wm * 32 + m * 16 + r16;
                const int off = ((ks * 4 + g) * 16) ^ ((row & 7) << 4);
                af[m] = *(const s16x8*)((const char*)Ab + row * 128 + off);
            }
#pragma unroll
            for (int n = 0; n < 4; ++n) {
                const int row = wn * 64 + n * 16 + r16;
                const int off = ((ks * 4 + g) * 16) ^ ((row & 7) << 4);
                bfr[n] = *(const s16x8*)((const char*)Bb + row * 128 + off);
            }
#pragma unroll
            for (int m = 0; m < 2; ++m)
#pragma unroll
                for (int n = 0; n < 4; ++n)
                    acc[m][n] = __builtin_amdgcn_mfma_f32_16x16x32_bf16(af[m], bfr[n], acc[m][n], 0, 0, 0);
        }
        asm volatile("s_waitcnt lgkmcnt(0)" ::: "memory");
        __builtin_amdgcn_s_barrier();
        asm volatile("" ::: "memory");
    }

    // ---- phase-1 epilogue: bias + relu + bf16 -> P (XOR-swizzled) ----
#pragma unroll
    for (int n = 0; n < 4; ++n) {
        const int col = wn * 64 + n * 16 + r16;
        const float bv = (col < 200) ? b2[col] : 0.f;
#pragma unroll
        for (int m = 0; m < 2; ++m) {
#pragma unroll
            for (int r = 0; r < 4; ++r) {
                const int row = wm * 32 + m * 16 + g * 4 + r;
                float v = acc[m][n][r] + bv;
                v = v > 0.f ? v : 0.f;
                const int byte = row * 512 + ((col * 2) ^ ((row & 7) << 4));
                *(unsigned short*)((char*)P + byte) = f2bf(v);
            }
        }
    }

    // ---- phase 2: P(64x256) @ W3b(256x256) ----
    stage8<256>(W3b, 256, 0, 0, Bs[0], wid, lane);
    asm volatile("s_waitcnt lgkmcnt(0)" ::: "memory");  // P writes done
    __builtin_amdgcn_s_barrier();
    asm volatile("" ::: "memory");

    f32x4 acc2[2][4];
#pragma unroll
    for (int m = 0; m < 2; ++m)
#pragma unroll
        for (int n = 0; n < 4; ++n)
            acc2[m][n] = (f32x4){0.f, 0.f, 0.f, 0.f};

    for (int kt = 0; kt < 4; ++kt) {
        const int buf = kt & 1;
        if (kt + 1 < 4) {
            stage8<256>(W3b, 256, 0, kt + 1, Bs[buf ^ 1], wid, lane);
            asm volatile("s_waitcnt vmcnt(4)" ::: "memory");
        } else {
            asm volatile("s_waitcnt vmcnt(0)" ::: "memory");
        }
        __builtin_amdgcn_s_barrier();
        asm volatile("" ::: "memory");

        const unsigned short* Bb = Bs[buf];
#pragma unroll
        for (int ks = 0; ks < 2; ++ks) {
            s16x8 af[2], bfr[4];
#pragma unroll
            for (int m = 0; m < 2; ++m) {
                const int row = wm * 32 + m * 16 + r16;
                const int byte = row * 512 + ((kt * 128 + (ks * 4 + g) * 16) ^ ((row & 7) << 4));
                af[m] = *(const s16x8*)((const char*)P + byte);
            }
#pragma unroll
            for (int n = 0; n < 4; ++n) {
                const int row = wn * 64 + n * 16 + r16;
                const int off = ((ks * 4 + g) * 16) ^ ((row & 7) << 4);
                bfr[n] = *(const s16x8*)((const char*)Bb + row * 128 + off);
            }
#pragma unroll
            for (int m = 0; m < 2; ++m)
#pragma unroll
                for (int n = 0; n < 4; ++n)
                    acc2[m][n] = __builtin_amdgcn_mfma_f32_16x16x32_bf16(af[m], bfr[n], acc2[m][n], 0, 0, 0);
        }
        asm volatile("s_waitcnt lgkmcnt(0)" ::: "memory");
        __builtin_amdgcn_s_barrier();
        asm volatile("" ::: "memory");
    }

    // ---- tail dot ----
    float wlv[4], b3v[4];
#pragma unroll
    for (int n = 0; n < 4; ++n) {
        const int col = wn * 64 + n * 16 + r16;
        wlv[n] = (col < 200) ? Wl[1024 + col] : 0.f;
        b3v[n] = (col < 200) ? b3[col] : 0.f;
    }
#pragma unroll
    for (int m = 0; m < 2; ++m) {
#pragma unroll
        for (int r = 0; r < 4; ++r) {
            float s = 0.f;
#pragma unroll
            for (int n = 0; n < 4; ++n) {
                float v = acc2[m][n][r] + b3v[n];
                v = v > 0.f ? v : 0.f;
                s += v * wlv[n];
            }
            s += __shfl_xor(s, 1, 64);
            s += __shfl_xor(s, 2, 64);
            s += __shfl_xor(s, 4, 64);
            s += __shfl_xor(s, 8, 64);
            if (r16 == 0) part[wid][wm * 32 + m * 16 + g * 4 + r] = s;
        }
    }
    __syncthreads();

    // ---- final: cross-net Horner combine + sigmoid ----
    if (tid < 64) {
        const int row = rowBase + tid;
        const int wmr = (tid >> 5) << 2;
        const float t = part[wmr][tid] + part[wmr + 1][tid] +
                        part[wmr + 2][tid] + part[wmr + 3][tid];
        const float blv = bl[0];
        const float* zp = zparts + (size_t)row * 8;
        float4 zpa = *(const float4*)(zp);       // P3_0 P2_0 P1_0 P3_1
        float4 zpb = *(const float4*)(zp + 4);   // P2_1 P1_1 P0   s
        const float s = zpb.w;
        const float z0 = ((zpa.x * s + zpa.y + czz[0]) * s + zpa.z + czz[1]) * s
                         + zpb.z + czz[2] + t + blv;
        const float z1 = ((zpa.w * s + zpb.x + czz[3]) * s + zpb.y + czz[4]) * s
                         + zpb.z + czz[5] + t + blv;
        out[row]          = 1.f / (1.f + expf(-z0));
        out[B_ROWS + row] = 1.f / (1.f + expf(-z1));
    }
}

// ---------------------------------------------------------------------------
extern "C" void kernel_launch(void* const* d_in, const int* in_sizes, int n_in,
                              void* d_out, int out_size, void* d_ws, size_t ws_size,
                              hipStream_t stream) {
    const float* x  = (const float*)d_in[0];
    const float* W1 = (const float*)d_in[3];
    const float* b1 = (const float*)d_in[4];
    const float* W2 = (const float*)d_in[5];
    const float* b2 = (const float*)d_in[6];
    const float* W3 = (const float*)d_in[7];
    const float* b3 = (const float*)d_in[8];
    const float* Wl = (const float*)d_in[9];
    const float* bl = (const float*)d_in[10];
    const float* cw = (const float*)d_in[11];
    const float* cb = (const float*)d_in[12];
    float* out = (float*)d_out;

    unsigned short* d1  = (unsigned short*)d_ws;          // 16384 x 512
    unsigned short* W1b = d1 + (size_t)16384 * 512;       // 512 x 1024
    unsigned short* W2b = W1b + (size_t)512 * 1024;       // 256 x 512
    unsigned short* W3b = W2b + (size_t)256 * 512;        // 256 x 256
    float* zparts = (float*)(W3b + (size_t)256 * 256);    // 16384 x 8
    float* czz = zparts + (size_t)16384 * 8;              // 6

    // weight transpose + cross-net P-vectors/constants
    prep<<<178, 256, 0, stream>>>(W1, W2, W3, cw, cb, Wl, W1b, W2b, W3b, czz);

    // d1 = relu(x @ W1 + b1), x read as f32 directly; cross dots -> zparts
    gemm_xa<<<512, 256, 0, stream>>>(x, W1b, b1, d1, zparts);

    // d2/d3/tail/cross-combine/sigmoid fused
    tail_fused<<<256, 512, 0, stream>>>(d1, W2b, b2, W3b, b3, Wl, bl,
                                        zparts, czz, out);
}

// Round 9
// 52.015 us; speedup vs baseline: 1.2876x; 1.0479x over previous
//
#include <hip/hip_runtime.h>
#include <hip/hip_bf16.h>
#include <math.h>

#define B_ROWS 16384
#define DIM 1024

typedef __attribute__((ext_vector_type(8))) short s16x8;
typedef __attribute__((ext_vector_type(4))) float f32x4;

static __device__ __forceinline__ unsigned short f2bf(float f) {
    union { float f; unsigned u; } v; v.f = f;
    unsigned r = v.u + 0x7FFF + ((v.u >> 16) & 1);  // RNE
    return (unsigned short)(r >> 16);
}

// packed f32x2 -> bf16x2 (RNE), single HW instruction
static __device__ __forceinline__ unsigned cvt_pk_bf16(float lo, float hi) {
    unsigned r;
    asm volatile("v_cvt_pk_bf16_f32 %0, %1, %2" : "=v"(r) : "v"(lo), "v"(hi));
    return r;
}

// async global -> LDS, 16 bytes per lane; lds base wave-uniform, HW adds lane*16
static __device__ __forceinline__ void gload16(const unsigned short* g, unsigned short* l) {
    __builtin_amdgcn_global_load_lds(
        (const __attribute__((address_space(1))) unsigned int*)g,
        (__attribute__((address_space(3))) unsigned int*)l, 16, 0, 0);
}

// ---------------------------------------------------------------------------
// prep (178 blocks): weight transpose+convert+pad (64x64 LDS tiles) +
// cross-net P-vector rows into W1b spare rows + scalar constants czz[6].
// Cross-net closed form (exact algebra):
//   z_i = s^3(x.P3_i)+s^2(x.P2_i)+s(x.P1_i)+(x.Wl)+s^2 C2_i+s C1_i+C0_i
// W1b rows: 500:P3_0 501:P2_0 502:P1_0 503:P3_1 504:P2_1 505:P1_1 506:Wl
//           507:ones (row-sum s)  508-511: zero
// ---------------------------------------------------------------------------
__global__ __launch_bounds__(256) void prep(
    const float* __restrict__ W1, const float* __restrict__ W2,
    const float* __restrict__ W3,
    const float* __restrict__ cw, const float* __restrict__ cb,
    const float* __restrict__ Wl,
    unsigned short* __restrict__ W1b, unsigned short* __restrict__ W2b,
    unsigned short* __restrict__ W3b,
    float* __restrict__ czz) {
    __shared__ unsigned short tile[64][72];
    __shared__ float red[4][6];
    const int tid = threadIdx.x;
    const int blk = blockIdx.x;

    if (blk < 176) {
        const int w = blk;
        const float* src; unsigned short* dst;
        int kt, nt, Ksrc, Nsrc, ldDst;
        bool skipHi = false;
        if (w < 128)      { kt = w & 15;         nt = w >> 4;         src = W1; dst = W1b; Ksrc = 1024; Nsrc = 500; ldDst = 1024; skipHi = true; }
        else if (w < 160) { kt = (w - 128) & 7;  nt = (w - 128) >> 3; src = W2; dst = W2b; Ksrc = 500;  Nsrc = 200; ldDst = 512;  }
        else              { kt = (w - 160) & 3;  nt = (w - 160) >> 2; src = W3; dst = W3b; Ksrc = 200;  Nsrc = 200; ldDst = 256;  }
        const int k0 = kt << 6, n0 = nt << 6;
        {
            const int r = tid >> 2, c0 = (tid & 3) << 4;
            const int kk = k0 + r;
#pragma unroll
            for (int i = 0; i < 16; ++i) {
                const int nn = n0 + c0 + i;
                const float v = (kk < Ksrc && nn < Nsrc) ? src[(size_t)kk * Nsrc + nn] : 0.f;
                tile[r][c0 + i] = f2bf(v);
            }
        }
        __syncthreads();
        {
            const int n = tid >> 2, kc = (tid & 3) << 4;
            if (!(skipHi && (n0 + n) >= 500)) {   // rows 500-511 owned by blk 176
                unsigned short* o = dst + (size_t)(n0 + n) * ldDst + k0 + kc;
#pragma unroll
                for (int i = 0; i < 16; ++i) o[i] = tile[kc + i][n];
            }
        }
    } else if (blk == 176) {
        // ---- P-vector rows ----
#pragma unroll
        for (int q = 0; q < 4; ++q) {
            const int k = tid * 4 + q;
            const float wl = Wl[k];
            const float a1 = cw[k],         a2 = cw[1024 + k],  a3 = cw[2048 + k];
            const float d1_ = cw[3072 + k], d2_ = cw[4096 + k], d3_ = cw[5120 + k];
            W1b[(size_t)500 * 1024 + k] = f2bf(a1 * a2 * a3 * wl);
            W1b[(size_t)501 * 1024 + k] = f2bf(a2 * a3 * wl);
            W1b[(size_t)502 * 1024 + k] = f2bf(a3 * wl);
            W1b[(size_t)503 * 1024 + k] = f2bf(d1_ * d2_ * d3_ * wl);
            W1b[(size_t)504 * 1024 + k] = f2bf(d2_ * d3_ * wl);
            W1b[(size_t)505 * 1024 + k] = f2bf(d3_ * wl);
            W1b[(size_t)506 * 1024 + k] = f2bf(wl);
            W1b[(size_t)507 * 1024 + k] = 0x3F80;   // bf16 1.0
            W1b[(size_t)508 * 1024 + k] = 0;
            W1b[(size_t)509 * 1024 + k] = 0;
            W1b[(size_t)510 * 1024 + k] = 0;
            W1b[(size_t)511 * 1024 + k] = 0;
        }
    } else {
        // ---- C scalars (f32 exact) ----
        float c[6] = {0.f, 0.f, 0.f, 0.f, 0.f, 0.f};
#pragma unroll
        for (int q = 0; q < 4; ++q) {
            const int k = tid * 4 + q;
            const float wl = Wl[k];
            {
                const float w2 = cw[1024 + k], w3 = cw[2048 + k];
                const float b1 = cb[k], b2 = cb[1024 + k], b3 = cb[2048 + k];
                c[0] += w2 * w3 * b1 * wl;
                c[1] += w3 * b2 * wl;
                c[2] += b3 * wl;
            }
            {
                const float w2 = cw[4096 + k], w3 = cw[5120 + k];
                const float b1 = cb[3072 + k], b2 = cb[4096 + k], b3 = cb[5120 + k];
                c[3] += w2 * w3 * b1 * wl;
                c[4] += w3 * b2 * wl;
                c[5] += b3 * wl;
            }
        }
        const int lane = tid & 63, wv = tid >> 6;
#pragma unroll
        for (int j = 0; j < 6; ++j)
#pragma unroll
            for (int m = 1; m < 64; m <<= 1) c[j] += __shfl_xor(c[j], m, 64);
        if (lane == 0)
#pragma unroll
            for (int j = 0; j < 6; ++j) red[wv][j] = c[j];
        __syncthreads();
        if (tid < 6) czz[tid] = red[0][tid] + red[1][tid] + red[2][tid] + red[3][tid];
    }
}

// ---------------------------------------------------------------------------
// stage_tile (4-wave): global_load_lds dwordx4, pre-swizzled global source,
// linear LDS dest.  LDS: [row][64] bf16, 16B chunk c holds k-chunk c^(row&7).
// ---------------------------------------------------------------------------
template <int ROWS>
static __device__ __forceinline__ void stage_tile(
    const unsigned short* __restrict__ src, int K, int rowBase, int kt,
    unsigned short* lds, int w, int lane) {
    const int r8   = lane >> 3;
    const int slot = lane & 7;
#pragma unroll
    for (int q = 0; q < ROWS / 32; ++q) {
        const int blk   = q * 4 + w;
        const int row   = blk * 8 + r8;
        const int chunk = slot ^ (row & 7);
        const unsigned short* g = src + (size_t)(rowBase + row) * K + kt * 64 + chunk * 8;
        gload16(g, lds + blk * 512);
    }
}

// stage (8-wave / 512-thread variant)
template <int ROWS>
static __device__ __forceinline__ void stage8(
    const unsigned short* __restrict__ src, int K, int rowBase, int kt,
    unsigned short* lds, int w, int lane) {
    const int r8   = lane >> 3;
    const int slot = lane & 7;
#pragma unroll
    for (int q = 0; q < ROWS / 64; ++q) {
        const int blk   = q * 8 + w;
        const int row   = blk * 8 + r8;
        const int chunk = slot ^ (row & 7);
        const unsigned short* g = src + (size_t)(rowBase + row) * K + kt * 64 + chunk * 8;
        gload16(g, lds + blk * 512);
    }
}

// ---------------------------------------------------------------------------
// gemm_xa: d1 = relu(x @ W1 + b1) reading x as f32 DIRECTLY.
// Tile 128x128, BK=64, 4 waves (2x2).  Counted-vmcnt 2-barrier schedule with
// 2-deep A register pipeline:
//   iter kt: vmcnt(0)+bar  (B(kt) aged 1 iter -> cheap)
//            issue A(kt+2)->bank[kt&1], B(kt+1)->Bs[buf^1]
//            compute(kt)
//            cvt_write A(kt+1) (bank loads aged 1 iter -> free wait)
//            lgkmcnt(0)+bar
// A staging: 8 f32/thread, rows tid>>3 (+32/round), chunk (tid&7)^(row&7),
// ds_write_b128.  Cols 500-507 spill raw f32 accs to zparts (cross dots).
// ---------------------------------------------------------------------------
__global__ __launch_bounds__(256) void gemm_xa(
    const float* __restrict__ X,             // 16384 x 1024 f32
    const unsigned short* __restrict__ Bw,   // 512 x 1024 bf16 (N x K)
    const float* __restrict__ bias,          // b1 (500)
    unsigned short* __restrict__ C,          // 16384 x 512 bf16
    float* __restrict__ zparts) {            // B_ROWS x 8 f32
    constexpr int K = 1024, ldc = 512, BM = 128, nK = 16;
    __shared__ unsigned short As[2][BM * 64];
    __shared__ unsigned short Bs[2][128 * 64];

    const int tid  = threadIdx.x;
    const int lane = tid & 63;
    const int wid  = tid >> 6;
    const int wm   = wid >> 1;
    const int wn   = wid & 1;
    const int g    = lane >> 4;
    const int r16  = lane & 15;

    const int cpx = gridDim.x >> 3;
    const int swz = (blockIdx.x & 7) * cpx + (blockIdx.x >> 3);
    const int rowBase = (swz >> 2) * BM;       // 4 col tiles (512/128)
    const int colBase = (swz & 3) << 7;

    // A staging coords: 8 consecutive f32 per thread, 4 rounds of 32 rows
    const int arow = tid >> 3;                 // 0..31
    const int ak8  = tid & 7;                  // 8-f32 slice (16B bf16 chunk)
    const float* aSrc = X + (size_t)(rowBase + arow) * K + ak8 * 8;

    float4 bank0[8], bank1[8];                 // A(kt) lives in bank[kt&1]

    f32x4 acc[4][4];
#pragma unroll
    for (int m = 0; m < 4; ++m)
#pragma unroll
        for (int n = 0; n < 4; ++n)
            acc[m][n] = (f32x4){0.f, 0.f, 0.f, 0.f};

#define ISSUE_A(kt_, bank_)                                                   \
    {                                                                         \
        _Pragma("unroll")                                                     \
        for (int q = 0; q < 4; ++q) {                                         \
            const float* s_ = aSrc + (size_t)q * 32 * K + (kt_) * 64;         \
            bank_[q * 2]     = *(const float4*)(s_);                          \
            bank_[q * 2 + 1] = *(const float4*)(s_ + 4);                      \
        }                                                                     \
    }

#define CVT_WRITE_A(bank_, dst_)                                              \
    {                                                                         \
        _Pragma("unroll")                                                     \
        for (int q = 0; q < 4; ++q) {                                         \
            const int row_ = q * 32 + arow;                                   \
            const int ch_  = ak8 ^ (row_ & 7);                                \
            uint4 v_;                                                         \
            v_.x = cvt_pk_bf16(bank_[q * 2].x,     bank_[q * 2].y);           \
            v_.y = cvt_pk_bf16(bank_[q * 2].z,     bank_[q * 2].w);           \
            v_.z = cvt_pk_bf16(bank_[q * 2 + 1].x, bank_[q * 2 + 1].y);       \
            v_.w = cvt_pk_bf16(bank_[q * 2 + 1].z, bank_[q * 2 + 1].w);       \
            *(uint4*)((char*)(dst_) + row_ * 128 + ch_ * 16) = v_;            \
        }                                                                     \
    }

#define COMPUTE(Ab_, Bb_)                                                     \
    {                                                                         \
        _Pragma("unroll")                                                     \
        for (int ks = 0; ks < 2; ++ks) {                                      \
            s16x8 af[4], bfr[4];                                              \
            _Pragma("unroll")                                                 \
            for (int m = 0; m < 4; ++m) {                                     \
                const int row_ = wm * 64 + m * 16 + r16;                      \
                const int off_ = ((ks * 4 + g) * 16) ^ ((row_ & 7) << 4);     \
                af[m] = *(const s16x8*)((const char*)(Ab_) + row_ * 128 + off_); \
            }                                                                 \
            _Pragma("unroll")                                                 \
            for (int n = 0; n < 4; ++n) {                                     \
                const int row_ = wn * 64 + n * 16 + r16;                      \
                const int off_ = ((ks * 4 + g) * 16) ^ ((row_ & 7) << 4);     \
                bfr[n] = *(const s16x8*)((const char*)(Bb_) + row_ * 128 + off_); \
            }                                                                 \
            _Pragma("unroll")                                                 \
            for (int m = 0; m < 4; ++m)                                       \
                _Pragma("unroll")                                             \
                for (int n = 0; n < 4; ++n)                                   \
                    acc[m][n] = __builtin_amdgcn_mfma_f32_16x16x32_bf16(      \
                        af[m], bfr[n], acc[m][n], 0, 0, 0);                   \
        }                                                                     \
    }

    // ---- prologue: A(0)->bank0, A(1)->bank1, B(0)->Bs[0] ----
    ISSUE_A(0, bank0);
    asm volatile("" ::: "memory");
    ISSUE_A(1, bank1);
    asm volatile("" ::: "memory");
    stage_tile<128>(Bw, K, colBase, 0, Bs[0], wid, lane);
    asm volatile("s_waitcnt vmcnt(12)" ::: "memory");   // A(0) retired
    CVT_WRITE_A(bank0, As[0]);
    asm volatile("" ::: "memory");

    // ---- main loop, hand-unrolled x2 (nK = 16 even) ----
#define LOOP_ITER(kt_, bufA_, bufB_, oBufA_, oBufB_, ibank_, cbank_)          \
    {                                                                         \
        asm volatile("s_waitcnt vmcnt(0)" ::: "memory");                      \
        __builtin_amdgcn_s_barrier();                                         \
        asm volatile("" ::: "memory");                                        \
        if ((kt_) + 2 < nK) { ISSUE_A((kt_) + 2, ibank_); }                   \
        asm volatile("" ::: "memory");                                        \
        if ((kt_) + 1 < nK)                                                   \
            stage_tile<128>(Bw, K, colBase, (kt_) + 1, oBufB_, wid, lane);    \
        asm volatile("" ::: "memory");                                        \
        COMPUTE(bufA_, bufB_);                                                \
        if ((kt_) + 1 < nK) { CVT_WRITE_A(cbank_, oBufA_); }                  \
        asm volatile("s_waitcnt lgkmcnt(0)" ::: "memory");                    \
        __builtin_amdgcn_s_barrier();                                         \
        asm volatile("" ::: "memory");                                        \
    }

    for (int kt = 0; kt < nK; kt += 2) {
        LOOP_ITER(kt,     As[0], Bs[0], As[1], Bs[1], bank0, bank1);
        LOOP_ITER(kt + 1, As[1], Bs[1], As[0], Bs[0], bank1, bank0);
    }
#undef LOOP_ITER
#undef COMPUTE
#undef CVT_WRITE_A
#undef ISSUE_A

    // ---- epilogue: bias + relu + bf16 store; cols 500-507 -> zparts raw ----
#pragma unroll
    for (int n = 0; n < 4; ++n) {
        const int col = colBase + wn * 64 + n * 16 + r16;
        const float bv = (col < 500) ? bias[col] : 0.f;
        const unsigned pc = (unsigned)(col - 500);
#pragma unroll
        for (int m = 0; m < 4; ++m) {
            const int rowB = rowBase + wm * 64 + m * 16 + g * 4;
#pragma unroll
            for (int r = 0; r < 4; ++r) {
                const float raw = acc[m][n][r];
                float v = raw + bv;
                v = v > 0.f ? v : 0.f;
                C[(size_t)(rowB + r) * ldc + col] = f2bf(v);
                if (pc < 8u) zparts[(size_t)(rowB + r) * 8 + pc] = raw;
            }
        }
    }
}

// ---------------------------------------------------------------------------
// tail_fused (8 waves / 512 threads, 2M x 4N wave grid): per 64-row block —
//   phase 1: P = relu(d1[64x512] @ W2b^T + b2)  (64x256 bf16 in LDS)
//   phase 2: acc2 = P @ W3b^T
//   epilogue: tail = relu(acc2 + b3) . Wl[1024:]
//   final: z_i = Horner(zparts, s) + czz_i + tail + bl; out = sigmoid(z_i)
// ---------------------------------------------------------------------------
__global__ __launch_bounds__(512) void tail_fused(
    const unsigned short* __restrict__ d1,   // 16384 x 512 bf16
    const unsigned short* __restrict__ W2b,  // 256 x 512 bf16 (N x K)
    const float* __restrict__ b2,
    const unsigned short* __restrict__ W3b,  // 256 x 256 bf16 (N x K)
    const float* __restrict__ b3,
    const float* __restrict__ Wl,            // 1224 floats
    const float* __restrict__ bl,
    const float* __restrict__ zparts,        // B_ROWS x 8
    const float* __restrict__ czz,           // 6
    float* __restrict__ out) {
    __shared__ unsigned short As[2][64 * 64];
    __shared__ unsigned short Bs[2][256 * 64];
    __shared__ unsigned short P[64 * 256];
    __shared__ float part[8][64];

    const int tid  = threadIdx.x;
    const int lane = tid & 63;
    const int wid  = tid >> 6;     // 0..7
    const int wm   = wid >> 2;     // 0..1 (rows)
    const int wn   = wid & 3;      // 0..3 (cols)
    const int g    = lane >> 4;
    const int r16  = lane & 15;
    const int rowBase = blockIdx.x << 6;

    f32x4 acc[2][4];
#pragma unroll
    for (int m = 0; m < 2; ++m)
#pragma unroll
        for (int n = 0; n < 4; ++n)
            acc[m][n] = (f32x4){0.f, 0.f, 0.f, 0.f};

    // ---- phase 1: d1[64x512] @ W2b(256x512) ----
    stage8<64>(d1, 512, rowBase, 0, As[0], wid, lane);
    stage8<256>(W2b, 512, 0, 0, Bs[0], wid, lane);

    for (int kt = 0; kt < 8; ++kt) {
        const int buf = kt & 1;
        if (kt + 1 < 8) {
            stage8<64>(d1, 512, rowBase, kt + 1, As[buf ^ 1], wid, lane);
            stage8<256>(W2b, 512, 0, kt + 1, Bs[buf ^ 1], wid, lane);
            asm volatile("s_waitcnt vmcnt(5)" ::: "memory");
        } else {
            asm volatile("s_waitcnt vmcnt(0)" ::: "memory");
        }
        __builtin_amdgcn_s_barrier();
        asm volatile("" ::: "memory");

        const unsigned short* Ab = As[buf];
        const unsigned short* Bb = Bs[buf];
#pragma unroll
        for (int ks = 0; ks < 2; ++ks) {
            s16x8 af[2], bfr[4];
#pragma unroll
            for (int m = 0; m < 2; ++m) {
                const int row = wm * 32 + m * 16 + r16;
                const int off = ((ks * 4 + g) * 16) ^ ((row & 7) << 4);
                af[m] = *(const s16x8*)((const char*)Ab + row * 128 + off);
            }
#pragma unroll
            for (int n = 0; n < 4; ++n) {
                const int row = wn * 64 + n * 16 + r16;
                const int off = ((ks * 4 + g) * 16) ^ ((row & 7) << 4);
                bfr[n] = *(const s16x8*)((const char*)Bb + row * 128 + off);
            }
#pragma unroll
            for (int m = 0; m < 2; ++m)
#pragma unroll
                for (int n = 0; n < 4; ++n)
                    acc[m][n] = __builtin_amdgcn_mfma_f32_16x16x32_bf16(af[m], bfr[n], acc[m][n], 0, 0, 0);
        }
        asm volatile("s_waitcnt lgkmcnt(0)" ::: "memory");
        __builtin_amdgcn_s_barrier();
        asm volatile("" ::: "memory");
    }

    // ---- phase-1 epilogue: bias + relu + bf16 -> P (XOR-swizzled) ----
#pragma unroll
    for (int n = 0; n < 4; ++n) {
        const int col = wn * 64 + n * 16 + r16;
        const float bv = (col < 200) ? b2[col] : 0.f;
#pragma unroll
        for (int m = 0; m < 2; ++m) {
#pragma unroll
            for (int r = 0; r < 4; ++r) {
                const int row = wm * 32 + m * 16 + g * 4 + r;
                float v = acc[m][n][r] + bv;
                v = v > 0.f ? v : 0.f;
                const int byte = row * 512 + ((col * 2) ^ ((row & 7) << 4));
                *(unsigned short*)((char*)P + byte) = f2bf(v);
            }
        }
    }

    // ---- phase 2: P(64x256) @ W3b(256x256) ----
    stage8<256>(W3b, 256, 0, 0, Bs[0], wid, lane);
    asm volatile("s_waitcnt lgkmcnt(0)" ::: "memory");  // P writes done
    __builtin_amdgcn_s_barrier();
    asm volatile("" ::: "memory");

    f32x4 acc2[2][4];
#pragma unroll
    for (int m = 0; m < 2; ++m)
#pragma unroll
        for (int n = 0; n < 4; ++n)
            acc2[m][n] = (f32x4){0.f, 0.f, 0.f, 0.f};

    for (int kt = 0; kt < 4; ++kt) {
        const int buf = kt & 1;
        if (kt + 1 < 4) {
            stage8<256>(W3b, 256, 0, kt + 1, Bs[buf ^ 1], wid, lane);
            asm volatile("s_waitcnt vmcnt(4)" ::: "memory");
        } else {
            asm volatile("s_waitcnt vmcnt(0)" ::: "memory");
        }
        __builtin_amdgcn_s_barrier();
        asm volatile("" ::: "memory");

        const unsigned short* Bb = Bs[buf];
#pragma unroll
        for (int ks = 0; ks < 2; ++ks) {
            s16x8 af[2], bfr[4];
#pragma unroll
            for (int m = 0; m < 2; ++m) {
                const int row = wm * 32 + m * 16 + r16;
                const int byte = row * 512 + ((kt * 128 + (ks * 4 + g) * 16) ^ ((row & 7) << 4));
                af[m] = *(const s16x8*)((const char*)P + byte);
            }
#pragma unroll
            for (int n = 0; n < 4; ++n) {
                const int row = wn * 64 + n * 16 + r16;
                const int off = ((ks * 4 + g) * 16) ^ ((row & 7) << 4);
                bfr[n] = *(const s16x8*)((const char*)Bb + row * 128 + off);
            }
#pragma unroll
            for (int m = 0; m < 2; ++m)
#pragma unroll
                for (int n = 0; n < 4; ++n)
                    acc2[m][n] = __builtin_amdgcn_mfma_f32_16x16x32_bf16(af[m], bfr[n], acc2[m][n], 0, 0, 0);
        }
        asm volatile("s_waitcnt lgkmcnt(0)" ::: "memory");
        __builtin_amdgcn_s_barrier();
        asm volatile("" ::: "memory");
    }

    // ---- tail dot ----
    float wlv[4], b3v[4];
#pragma unroll
    for (int n = 0; n < 4; ++n) {
        const int col = wn * 64 + n * 16 + r16;
        wlv[n] = (col < 200) ? Wl[1024 + col] : 0.f;
        b3v[n] = (col < 200) ? b3[col] : 0.f;
    }
#pragma unroll
    for (int m = 0; m < 2; ++m) {
#pragma unroll
        for (int r = 0; r < 4; ++r) {
            float s = 0.f;
#pragma unroll
            for (int n = 0; n < 4; ++n) {
                float v = acc2[m][n][r] + b3v[n];
                v = v > 0.f ? v : 0.f;
                s += v * wlv[n];
            }
            s += __shfl_xor(s, 1, 64);
            s += __shfl_xor(s, 2, 64);
            s += __shfl_xor(s, 4, 64);
            s += __shfl_xor(s, 8, 64);
            if (r16 == 0) part[wid][wm * 32 + m * 16 + g * 4 + r] = s;
        }
    }
    __syncthreads();

    // ---- final: cross-net Horner combine + sigmoid ----
    if (tid < 64) {
        const int row = rowBase + tid;
        const int wmr = (tid >> 5) << 2;
        const float t = part[wmr][tid] + part[wmr + 1][tid] +
                        part[wmr + 2][tid] + part[wmr + 3][tid];
        const float blv = bl[0];
        const float* zp = zparts + (size_t)row * 8;
        float4 zpa = *(const float4*)(zp);       // P3_0 P2_0 P1_0 P3_1
        float4 zpb = *(const float4*)(zp + 4);   // P2_1 P1_1 P0   s
        const float s = zpb.w;
        const float z0 = ((zpa.x * s + zpa.y + czz[0]) * s + zpa.z + czz[1]) * s
                         + zpb.z + czz[2] + t + blv;
        const float z1 = ((zpa.w * s + zpb.x + czz[3]) * s + zpb.y + czz[4]) * s
                         + zpb.z + czz[5] + t + blv;
        out[row]          = 1.f / (1.f + expf(-z0));
        out[B_ROWS + row] = 1.f / (1.f + expf(-z1));
    }
}

// ---------------------------------------------------------------------------
extern "C" void kernel_launch(void* const* d_in, const int* in_sizes, int n_in,
                              void* d_out, int out_size, void* d_ws, size_t ws_size,
                              hipStream_t stream) {
    const float* x  = (const float*)d_in[0];
    const float* W1 = (const float*)d_in[3];
    const float* b1 = (const float*)d_in[4];
    const float* W2 = (const float*)d_in[5];
    const float* b2 = (const float*)d_in[6];
    const float* W3 = (const float*)d_in[7];
    const float* b3 = (const float*)d_in[8];
    const float* Wl = (const float*)d_in[9];
    const float* bl = (const float*)d_in[10];
    const float* cw = (const float*)d_in[11];
    const float* cb = (const float*)d_in[12];
    float* out = (float*)d_out;

    unsigned short* d1  = (unsigned short*)d_ws;          // 16384 x 512
    unsigned short* W1b = d1 + (size_t)16384 * 512;       // 512 x 1024
    unsigned short* W2b = W1b + (size_t)512 * 1024;       // 256 x 512
    unsigned short* W3b = W2b + (size_t)256 * 512;        // 256 x 256
    float* zparts = (float*)(W3b + (size_t)256 * 256);    // 16384 x 8
    float* czz = zparts + (size_t)16384 * 8;              // 6

    // weight transpose + cross-net P-vectors/constants
    prep<<<178, 256, 0, stream>>>(W1, W2, W3, cw, cb, Wl, W1b, W2b, W3b, czz);

    // d1 = relu(x @ W1 + b1), x read as f32 directly; cross dots -> zparts
    gemm_xa<<<512, 256, 0, stream>>>(x, W1b, b1, d1, zparts);

    // d2/d3/tail/cross-combine/sigmoid fused
    tail_fused<<<256, 512, 0, stream>>>(d1, W2b, b2, W3b, b3, Wl, bl,
                                        zparts, czz, out);
}